// Round 4
// baseline (560.293 us; speedup 1.0000x reference)
//
#include <hip/hip_runtime.h>

#define NB 65536     // groups per batch
#define NBLK 512     // persistent-ish: 2 blocks/CU x 256 CU, all co-resident
#define ITERS 8      // NBLK * ITERS * 16 groups = 65536

// Reduce-scatter a 4-vector over the 32-lane group, all by value.
// Returns full 32-lane sum of feature f4 = 2*(t&1) + ((t>>1)&1).
__device__ __forceinline__ float rs4v(float v0, float v1, float v2, float v3,
                                      bool b0, bool b1) {
    float s, r;
    s = b0 ? v0 : v2; r = __shfl_xor(s, 1); float w0 = (b0 ? v2 : v0) + r;
    s = b0 ? v1 : v3; r = __shfl_xor(s, 1); float w1 = (b0 ? v3 : v1) + r;
    s = b1 ? w0 : w1; r = __shfl_xor(s, 2); float u  = (b1 ? w1 : w0) + r;
    u += __shfl_xor(u, 4);
    u += __shfl_xor(u, 8);
    u += __shfl_xor(u, 16);
    return u;
}

// Reduce-scatter an 8-vector over 32 lanes.
// Returns full sum of feature f8 = 4*(t&1) + (t&2) + ((t>>2)&1).
__device__ __forceinline__ float rs8v(float v0, float v1, float v2, float v3,
                                      float v4, float v5, float v6, float v7,
                                      bool b0, bool b1, bool b2) {
    float s, r;
    s = b0 ? v0 : v4; r = __shfl_xor(s, 1); float w0 = (b0 ? v4 : v0) + r;
    s = b0 ? v1 : v5; r = __shfl_xor(s, 1); float w1 = (b0 ? v5 : v1) + r;
    s = b0 ? v2 : v6; r = __shfl_xor(s, 1); float w2 = (b0 ? v6 : v2) + r;
    s = b0 ? v3 : v7; r = __shfl_xor(s, 1); float w3 = (b0 ? v7 : v3) + r;
    s = b1 ? w0 : w2; r = __shfl_xor(s, 2); float x0 = (b1 ? w2 : w0) + r;
    s = b1 ? w1 : w3; r = __shfl_xor(s, 2); float x1 = (b1 ? w3 : w1) + r;
    s = b2 ? x0 : x1; r = __shfl_xor(s, 4); float u = (b2 ? x1 : x0) + r;
    u += __shfl_xor(u, 8);
    u += __shfl_xor(u, 16);
    return u;
}

// Per-iteration pipelined state: 2 groups per 32-lane group.
// mbr/itv double-buffer across iterations; mbr[cur] dies at g_att so the
// allocator reuses those 64 VGPRs for mbr[nxt] (loads issued during pred).
struct GState {
    int g0, g1, it0, it1;
    int4 m0, m1;
    float mbr[2][4][8];
    float itv[2][8];
};

struct Ctx {
    const int* group_inputs; const int* item_inputs; const int* group_members;
    const float* user_emb; const float* item_emb; const float* group_emb;
    float ab1v[4], aw2v[4];
    float pb1v, pw2v, pb2v, cw0, cw1, cb0c, cb1c;
    bool bb0, bb1, bb2;
    int t, lg;
    float* out;
};

__device__ __forceinline__ void load_idx(const Ctx& c, GState& st, int b) {
    st.g0  = c.group_inputs[b];  st.g1  = c.group_inputs[b + 1];
    st.it0 = c.item_inputs[b];   st.it1 = c.item_inputs[b + 1];
}

__device__ __forceinline__ void load_mem(const Ctx& c, GState& st) {
    st.m0 = ((const int4*)c.group_members)[st.g0];
    st.m1 = ((const int4*)c.group_members)[st.g1];
}

__device__ __forceinline__ void load_rows(const Ctx& c, GState& st) {
    const int t = c.t;
    const int mi[2][4] = {{st.m0.x, st.m0.y, st.m0.z, st.m0.w},
                          {st.m1.x, st.m1.y, st.m1.z, st.m1.w}};
    #pragma unroll
    for (int gg = 0; gg < 2; ++gg) {
        #pragma unroll
        for (int s = 0; s < 4; ++s) {
            const float4* p = (const float4*)c.user_emb + (((long)mi[gg][s]) << 6) + (t << 1);
            float4 v0 = p[0], v1 = p[1];
            st.mbr[gg][s][0] = v0.x; st.mbr[gg][s][1] = v0.y;
            st.mbr[gg][s][2] = v0.z; st.mbr[gg][s][3] = v0.w;
            st.mbr[gg][s][4] = v1.x; st.mbr[gg][s][5] = v1.y;
            st.mbr[gg][s][6] = v1.z; st.mbr[gg][s][7] = v1.w;
        }
    }
    const int ii2[2] = {st.it0, st.it1};
    #pragma unroll
    for (int gg = 0; gg < 2; ++gg) {
        const float4* p = (const float4*)c.item_emb + (((long)ii2[gg]) << 6) + (t << 1);
        float4 v0 = p[0], v1 = p[1];
        st.itv[gg][0] = v0.x; st.itv[gg][1] = v0.y;
        st.itv[gg][2] = v0.z; st.itv[gg][3] = v0.w;
        st.itv[gg][4] = v1.x; st.itv[gg][5] = v1.y;
        st.itv[gg][6] = v1.z; st.itv[gg][7] = v1.w;
    }
}

// One iteration: compute 2 groups from `cur` while prefetching `nxt`.
// No barriers anywhere in here — LDS weights are read-only after the
// one-time staging sync.
__device__ __forceinline__ void iter_body(const Ctx& c, GState& cur, GState& nxt,
                                          int k, int base,
                                          const float* sA, const float* sP) {
    const int t = c.t;
    const int b0 = base + k * 16 + c.lg * 2;
    const bool more = (k + 1 < ITERS);
    if (more) load_idx(c, nxt, b0 + 16);     // level-1 indices for next iter

    // group-emb rows for CURRENT iter: issued now, consumed at g_att
    // (~2500 cycles of att compute hides the gather latency)
    float gvr[2][8];
    {
        const int gi2[2] = {cur.g0, cur.g1};
        #pragma unroll
        for (int gg = 0; gg < 2; ++gg) {
            const float4* p = (const float4*)c.group_emb + (((long)gi2[gg]) << 6) + (t << 1);
            float4 v0 = p[0], v1 = p[1];
            gvr[gg][0] = v0.x; gvr[gg][1] = v0.y; gvr[gg][2] = v0.z; gvr[gg][3] = v0.w;
            gvr[gg][4] = v1.x; gvr[gg][5] = v1.y; gvr[gg][6] = v1.z; gvr[gg][7] = v1.w;
        }
    }

    // ---- attention MLP: 4 passes of 4 hidden units, weights shared by 2 groups ----
    const float* mbase = sA + 260 * (t >> 1) + ((t & 1) << 7);
    const float* ibase = mbase + 260 * 16;
    float logit[2][4] = {{0.f, 0.f, 0.f, 0.f}, {0.f, 0.f, 0.f, 0.f}};
    #pragma unroll
    for (int p = 0; p < 4; ++p) {
        float acc[2][4][4], pi[2][4];
        #pragma unroll
        for (int gg = 0; gg < 2; ++gg) {
            #pragma unroll
            for (int f = 0; f < 4; ++f) {
                pi[gg][f] = 0.f;
                #pragma unroll
                for (int s = 0; s < 4; ++s) acc[gg][s][f] = 0.f;
            }
        }
        #pragma unroll
        for (int j = 0; j < 8; ++j) {
            float4 wm = *(const float4*)(mbase + (j << 4) + (p << 2));
            float4 wi = *(const float4*)(ibase + (j << 4) + (p << 2));
            #pragma unroll
            for (int gg = 0; gg < 2; ++gg) {
                #pragma unroll
                for (int s = 0; s < 4; ++s) {
                    float mv = cur.mbr[gg][s][j];
                    acc[gg][s][0] += mv * wm.x; acc[gg][s][1] += mv * wm.y;
                    acc[gg][s][2] += mv * wm.z; acc[gg][s][3] += mv * wm.w;
                }
                float iv = cur.itv[gg][j];
                pi[gg][0] += iv * wi.x; pi[gg][1] += iv * wi.y;
                pi[gg][2] += iv * wi.z; pi[gg][3] += iv * wi.w;
            }
        }
        #pragma unroll
        for (int gg = 0; gg < 2; ++gg) {
            float hb = rs4v(pi[gg][0], pi[gg][1], pi[gg][2], pi[gg][3], c.bb0, c.bb1)
                       + c.ab1v[p];
            #pragma unroll
            for (int s = 0; s < 4; ++s) {
                float h = rs4v(acc[gg][s][0], acc[gg][s][1], acc[gg][s][2], acc[gg][s][3],
                               c.bb0, c.bb1) + hb;
                logit[gg][s] += fmaxf(h, 0.f) * c.aw2v[p];
            }
        }
    }
    if (more) load_mem(c, nxt);              // level-2 (dependent) index for next iter

    // quad all-reduce: each quad holds each pass's 4 features exactly once
    #pragma unroll
    for (int gg = 0; gg < 2; ++gg) {
        #pragma unroll
        for (int s = 0; s < 4; ++s) {
            float v = logit[gg][s];
            v += __shfl_xor(v, 1); v += __shfl_xor(v, 2);
            logit[gg][s] = v;
        }
    }

    // ---- softmax over 4 members, argmax, classifier ----
    float at[2][4]; int bestv[2], pcv[2];
    #pragma unroll
    for (int gg = 0; gg < 2; ++gg) {
        float l0 = logit[gg][0], l1 = logit[gg][1], l2 = logit[gg][2], l3 = logit[gg][3];
        float mx = fmaxf(fmaxf(l0, l1), fmaxf(l2, l3));
        float e0 = __expf(l0 - mx), e1 = __expf(l1 - mx);
        float e2 = __expf(l2 - mx), e3 = __expf(l3 - mx);
        float inv = 1.f / (e0 + e1 + e2 + e3);
        at[gg][0] = e0 * inv; at[gg][1] = e1 * inv;
        at[gg][2] = e2 * inv; at[gg][3] = e3 * inv;
        int best = 0; float bv = at[gg][0];
        if (at[gg][1] > bv) { bv = at[gg][1]; best = 1; }
        if (at[gg][2] > bv) { bv = at[gg][2]; best = 2; }
        if (at[gg][3] > bv) { bv = at[gg][3]; best = 3; }
        bestv[gg] = best;
        pcv[gg] = (bv * c.cw1 + c.cb1c) > (bv * c.cw0 + c.cb0c) ? 1 : 0;
    }

    if (t == 0) {
        #pragma unroll
        for (int gg = 0; gg < 2; ++gg) {
            const int b = b0 + gg;
            *(float4*)(c.out + NB + 4 * b) = make_float4(at[gg][0], at[gg][1], at[gg][2], at[gg][3]);
            c.out[5 * NB + b] = (float)pcv[gg];
        }
    }

    // ---- g_att (cur.mbr and gvr die here) ----
    float gvec[2][8], elv[2][8];
    #pragma unroll
    for (int gg = 0; gg < 2; ++gg) {
        #pragma unroll
        for (int d = 0; d < 8; ++d) {
            float w = at[gg][0] * cur.mbr[gg][0][d] + at[gg][1] * cur.mbr[gg][1][d]
                    + at[gg][2] * cur.mbr[gg][2][d] + at[gg][3] * cur.mbr[gg][3][d];
            float ldr = cur.mbr[gg][0][d];
            ldr = (bestv[gg] == 1) ? cur.mbr[gg][1][d] : ldr;
            ldr = (bestv[gg] == 2) ? cur.mbr[gg][2][d] : ldr;
            ldr = (bestv[gg] == 3) ? cur.mbr[gg][3][d] : ldr;
            float ga = pcv[gg] ? ldr : w;
            float gv = ga + gvr[gg][d];
            gvec[gg][d] = gv;
            elv[gg][d]  = gv * cur.itv[gg][d];
        }
    }

    // next iter's embedding rows: issued now, latency hides under pred MLP;
    // the allocator reuses cur.mbr's registers (dead above) for nxt.mbr
    if (more) load_rows(c, nxt);

    // ---- prediction MLP: [elem, g, items] (3*256) -> 8 -> 1, weights shared ----
    const float* pbase = sP + 132 * (t >> 1) + ((t & 1) << 6);
    float po[2][8] = {{0.f,0.f,0.f,0.f,0.f,0.f,0.f,0.f},
                      {0.f,0.f,0.f,0.f,0.f,0.f,0.f,0.f}};
    #pragma unroll
    for (int j = 0; j < 8; ++j) {
        const float* pA = pbase + (j << 3);
        float4 a0 = *(const float4*)pA,          a1 = *(const float4*)(pA + 4);
        float4 q0 = *(const float4*)(pA + 2112), q1 = *(const float4*)(pA + 2116);
        float4 c0 = *(const float4*)(pA + 4224), c1 = *(const float4*)(pA + 4228);
        #pragma unroll
        for (int gg = 0; gg < 2; ++gg) {
            float e = elv[gg][j], gv = gvec[gg][j], iv = cur.itv[gg][j];
            po[gg][0] += e * a0.x; po[gg][0] += gv * q0.x; po[gg][0] += iv * c0.x;
            po[gg][1] += e * a0.y; po[gg][1] += gv * q0.y; po[gg][1] += iv * c0.y;
            po[gg][2] += e * a0.z; po[gg][2] += gv * q0.z; po[gg][2] += iv * c0.z;
            po[gg][3] += e * a0.w; po[gg][3] += gv * q0.w; po[gg][3] += iv * c0.w;
            po[gg][4] += e * a1.x; po[gg][4] += gv * q1.x; po[gg][4] += iv * c1.x;
            po[gg][5] += e * a1.y; po[gg][5] += gv * q1.y; po[gg][5] += iv * c1.y;
            po[gg][6] += e * a1.z; po[gg][6] += gv * q1.z; po[gg][6] += iv * c1.z;
            po[gg][7] += e * a1.w; po[gg][7] += gv * q1.w; po[gg][7] += iv * c1.w;
        }
    }

    float yv[2];
    #pragma unroll
    for (int gg = 0; gg < 2; ++gg) {
        float poR = rs8v(po[gg][0], po[gg][1], po[gg][2], po[gg][3],
                         po[gg][4], po[gg][5], po[gg][6], po[gg][7],
                         c.bb0, c.bb1, c.bb2);
        float z = fmaxf(poR + c.pb1v, 0.f) * c.pw2v;
        z += __shfl_xor(z, 1); z += __shfl_xor(z, 2); z += __shfl_xor(z, 4);
        z += c.pb2v;
        yv[gg] = 1.f / (1.f + __expf(-z));
    }

    if (t == 0) {
        c.out[b0]     = yv[0];
        c.out[b0 + 1] = yv[1];
    }
}

// NOTE: no min-waves arg (prev session: __launch_bounds__(256,4) clamped to the
// 64-VGPR tier -> spills). LDS = 58624 B -> 2 blocks/CU; VGPR free up to 256.
__global__ __launch_bounds__(256) void agree_kernel(
    const int* __restrict__ group_inputs,
    const int* __restrict__ item_inputs,
    const int* __restrict__ group_members,
    const float* __restrict__ user_emb,
    const float* __restrict__ item_emb,
    const float* __restrict__ group_emb,
    const float* __restrict__ att_w1,
    const float* __restrict__ att_b1,
    const float* __restrict__ att_w2,
    const float* __restrict__ att_b2,
    const float* __restrict__ cls_w,
    const float* __restrict__ cls_b,
    const float* __restrict__ pred_w1,
    const float* __restrict__ pred_b1,
    const float* __restrict__ pred_w2,
    const float* __restrict__ pred_b2,
    float* __restrict__ out)
{
    // Both weight buffers resident simultaneously -> staged ONCE, one barrier
    // total, zero barriers in the main loop.
    //   sA: att_w1 [512][16] as 32 chunks of 16 rows, chunk stride 260
    //   sP: pred_w1 [768][8] as 48 chunks of 16 rows, chunk stride 132
    __shared__ __align__(16) float sA[32 * 260];
    __shared__ __align__(16) float sP[48 * 132];

    const int tid = threadIdx.x;
    const int t = tid & 31;                 // lane within group (owns dims 8t..8t+7)
    const int lg = tid >> 5;
    const int base = blockIdx.x * (ITERS * 16);

    // ---- one-time weight staging ----
    {
        const float4* src = (const float4*)att_w1;       // 2048 float4
        for (int i = tid; i < 2048; i += 256) {
            float4 v = src[i];
            int r = i >> 2, cb = (i & 3) << 2;
            *(float4*)(sA + 260 * (r >> 4) + ((r & 15) << 4) + cb) = v;
        }
        const float4* srcp = (const float4*)pred_w1;     // 1536 float4
        for (int i = tid; i < 1536; i += 256) {
            float4 v = srcp[i];
            int r = i >> 1, cb = (i & 1) << 2;
            *(float4*)(sP + 132 * (r >> 4) + ((r & 15) << 3) + cb) = v;
        }
    }

    Ctx c;
    c.group_inputs = group_inputs; c.item_inputs = item_inputs;
    c.group_members = group_members;
    c.user_emb = user_emb; c.item_emb = item_emb; c.group_emb = group_emb;
    c.t = t; c.lg = lg; c.out = out;
    c.bb0 = (t & 1); c.bb1 = (t & 2); c.bb2 = (t & 4);
    const int f4 = ((t & 1) << 1) | ((t >> 1) & 1);            // rs4v output feature
    const int f8 = ((t & 1) << 2) + (t & 2) + ((t >> 2) & 1);  // rs8v output feature
    #pragma unroll
    for (int p = 0; p < 4; ++p) {
        c.ab1v[p] = att_b1[4 * p + f4];
        c.aw2v[p] = att_w2[4 * p + f4];
    }
    c.pb1v = pred_b1[f8]; c.pw2v = pred_w2[f8]; c.pb2v = pred_b2[0];
    c.cw0 = cls_w[0]; c.cw1 = cls_w[1]; c.cb0c = cls_b[0]; c.cb1c = cls_b[1];

    // ---- prologue: pipeline fill for iteration 0 (overlaps the barrier wait) ----
    GState sa, sb;
    load_idx(c, sa, base + lg * 2);
    load_mem(c, sa);
    load_rows(c, sa);

    __syncthreads();    // the only barrier in the kernel

    // ---- main loop: 2-stage software pipeline, ping-pong register buffers ----
    for (int kk = 0; kk < ITERS; kk += 2) {
        iter_body(c, sa, sb, kk,     base, sA, sP);
        iter_body(c, sb, sa, kk + 1, base, sA, sP);
    }
}

extern "C" void kernel_launch(void* const* d_in, const int* in_sizes, int n_in,
                              void* d_out, int out_size, void* d_ws, size_t ws_size,
                              hipStream_t stream) {
    (void)in_sizes; (void)n_in; (void)out_size; (void)d_ws; (void)ws_size;
    agree_kernel<<<NBLK, 256, 0, stream>>>(
        (const int*)d_in[0], (const int*)d_in[1], (const int*)d_in[2],
        (const float*)d_in[3], (const float*)d_in[4], (const float*)d_in[5],
        (const float*)d_in[6], (const float*)d_in[7], (const float*)d_in[8],
        (const float*)d_in[9], (const float*)d_in[10], (const float*)d_in[11],
        (const float*)d_in[12], (const float*)d_in[13], (const float*)d_in[14],
        (const float*)d_in[15], (float*)d_out);
}

// Round 5
// 427.369 us; speedup vs baseline: 1.3110x; 1.3110x over previous
//
#include <hip/hip_runtime.h>

#define NB 65536     // groups per batch
#define GPB 8        // groups per block (256 threads, 32 lanes/group)

// ---- DPP cross-lane helpers (VALU pipe, zero DS-pipe traffic) ----
// quad_perm[1,0,3,2] = xor1, quad_perm[2,3,0,1] = xor2,
// row_ror:4/8 = rotate within 16-lane row (plain-accumulate steps only).
#define QP_X1 0xB1
#define QP_X2 0x4E
#define ROR4  0x124
#define ROR8  0x128
template<int CTRL>
__device__ __forceinline__ float fdpp(float x) {
    return __int_as_float(__builtin_amdgcn_mov_dpp(__float_as_int(x), CTRL, 0xF, 0xF, true));
}

// Reduce-scatter 4 features over the 32-lane group. 1 DS op (xor16), rest VALU.
// Output: lane t holds full sum of feature f4 = 2*(t&1) + ((t>>1)&1).
// Levels: xor1/xor2 scatter via quad_perm; bits 2,3 via rotate-accumulate
// (ror4+ror8 sum the 4 mod-4-congruent lanes of the row); bit4 via ds_swizzle.
__device__ __forceinline__ float rs4d(float v0, float v1, float v2, float v3,
                                      bool b0, bool b1) {
    float s, r;
    s = b0 ? v0 : v2; r = fdpp<QP_X1>(s); float w0 = (b0 ? v2 : v0) + r;
    s = b0 ? v1 : v3; r = fdpp<QP_X1>(s); float w1 = (b0 ? v3 : v1) + r;
    s = b1 ? w0 : w1; r = fdpp<QP_X2>(s); float u  = (b1 ? w1 : w0) + r;
    u += fdpp<ROR4>(u);
    u += fdpp<ROR8>(u);
    u += __shfl_xor(u, 16);
    return u;
}

// Reduce-scatter 8 features over 32 lanes. 1 DS op.
// Scatter levels: bit0 (quad_perm), bit1 (quad_perm), bit4 (ds_swizzle xor16);
// plain levels: bits 2,3 via ror4+ror8.
// Output: lane t holds full sum of feature f8n = 4*(t&1) + (t&2) + ((t>>4)&1).
__device__ __forceinline__ float rs8d(float v0, float v1, float v2, float v3,
                                      float v4, float v5, float v6, float v7,
                                      bool b0, bool b1, bool b4) {
    float s, r;
    s = b0 ? v0 : v4; r = fdpp<QP_X1>(s); float w0 = (b0 ? v4 : v0) + r;
    s = b0 ? v1 : v5; r = fdpp<QP_X1>(s); float w1 = (b0 ? v5 : v1) + r;
    s = b0 ? v2 : v6; r = fdpp<QP_X1>(s); float w2 = (b0 ? v6 : v2) + r;
    s = b0 ? v3 : v7; r = fdpp<QP_X1>(s); float w3 = (b0 ? v7 : v3) + r;
    s = b1 ? w0 : w2; r = fdpp<QP_X2>(s); float x0 = (b1 ? w2 : w0) + r;
    s = b1 ? w1 : w3; r = fdpp<QP_X2>(s); float x1 = (b1 ? w3 : w1) + r;
    s = b4 ? x0 : x1; r = __shfl_xor(s, 16); float u = (b4 ? x1 : x0) + r;
    u += fdpp<ROR4>(u);
    u += fdpp<ROR8>(u);
    return u;
}

// NOTE: no min-waves arg. __launch_bounds__(256, 4) made the allocator clamp
// to the 64-VGPR tier -> spills (prev session). R4 lesson: 2-deep register
// pipelining spills at VGPR=256 -> 48 MB scratch writes. Keep R0 structure.
__global__ __launch_bounds__(256) void agree_kernel(
    const int* __restrict__ group_inputs,
    const int* __restrict__ item_inputs,
    const int* __restrict__ group_members,
    const float* __restrict__ user_emb,
    const float* __restrict__ item_emb,
    const float* __restrict__ group_emb,
    const float* __restrict__ att_w1,
    const float* __restrict__ att_b1,
    const float* __restrict__ att_w2,
    const float* __restrict__ att_b2,
    const float* __restrict__ cls_w,
    const float* __restrict__ cls_b,
    const float* __restrict__ pred_w1,
    const float* __restrict__ pred_b1,
    const float* __restrict__ pred_w2,
    const float* __restrict__ pred_b2,
    float* __restrict__ out)
{
    // Phase-split LDS union (35328 B -> 4 blocks/CU by LDS).
    // Bank-conflict-free layout: chunk stride ≡ 20, parity half-offset ≡ 16
    // (mod 32 floats) -> each consecutive-8-lane phase of a ds_read_b128 hits
    // all 8 bank-quads exactly once (old 260/128 layout: 2 lanes/quad).
    //   phase A: att_w1 [512][16]  as 32 chunks {rows 16c..16c+15}: chunk 276,
    //            half (rows 8t..8t+7 for lane parity) at +144
    //   phase B: pred_w1 [768][8] as 48 chunks: chunk 148, half at +80
    __shared__ __align__(16) float sBuf[32 * 276];

    const int tid = threadIdx.x;
    const int t = tid & 31;                 // lane within group (owns dims 8t..8t+7)
    const int b = blockIdx.x * GPB + (tid >> 5);

    // ---- issue gathers early (latency hides under weight staging) ----
    const int g  = group_inputs[b];
    const int it = item_inputs[b];
    const int4 mem = ((const int4*)group_members)[g];

    float mbr[4][8];
    {
        const int mi[4] = {mem.x, mem.y, mem.z, mem.w};
        #pragma unroll
        for (int s = 0; s < 4; ++s) {
            const float4* p = (const float4*)user_emb + (((long)mi[s]) << 6) + (t << 1);
            float4 v0 = p[0], v1 = p[1];
            mbr[s][0] = v0.x; mbr[s][1] = v0.y; mbr[s][2] = v0.z; mbr[s][3] = v0.w;
            mbr[s][4] = v1.x; mbr[s][5] = v1.y; mbr[s][6] = v1.z; mbr[s][7] = v1.w;
        }
    }
    float itv[8];
    {
        const float4* p = (const float4*)item_emb + (((long)it) << 6) + (t << 1);
        float4 v0 = p[0], v1 = p[1];
        itv[0] = v0.x; itv[1] = v0.y; itv[2] = v0.z; itv[3] = v0.w;
        itv[4] = v1.x; itv[5] = v1.y; itv[6] = v1.z; itv[7] = v1.w;
    }

    const bool bb0 = (t & 1), bb1 = (t & 2), bb4 = (t & 16);
    const int f4  = ((t & 1) << 1) | ((t >> 1) & 1);             // rs4d output feature
    const int f8n = ((t & 1) << 2) + (t & 2) + ((t >> 4) & 1);   // rs8d output feature
    float ab1v[4], aw2v[4];
    #pragma unroll
    for (int p = 0; p < 4; ++p) {
        ab1v[p] = att_b1[4 * p + f4];
        aw2v[p] = att_w2[4 * p + f4];
    }
    const float pb1v = pred_b1[f8n], pw2v = pred_w2[f8n], pb2v = pred_b2[0];
    const float cw0 = cls_w[0], cw1 = cls_w[1], cb0 = cls_b[0], cb1 = cls_b[1];

    // ---- phase A: stage att_w1 ----
    {
        const float4* src = (const float4*)att_w1;       // 2048 float4
        for (int i = tid; i < 2048; i += 256) {
            float4 v = src[i];
            int r = i >> 2, cb = (i & 3) << 2;
            *(float4*)(sBuf + 276 * (r >> 4) + 144 * ((r >> 3) & 1) + ((r & 7) << 4) + cb) = v;
        }
    }
    __syncthreads();

    // ---- attention MLP: 4 passes of 4 hidden units ----
    const float* mbase = sBuf + 276 * (t >> 1) + 144 * (t & 1);  // member rows 8t..8t+7
    const float* ibase = mbase + 276 * 16;                       // item rows
    float logit[4] = {0.f, 0.f, 0.f, 0.f};
    #pragma unroll
    for (int p = 0; p < 4; ++p) {
        float acc[4][4], pi[4];
        #pragma unroll
        for (int f = 0; f < 4; ++f) {
            pi[f] = 0.f;
            #pragma unroll
            for (int s = 0; s < 4; ++s) acc[s][f] = 0.f;
        }
        #pragma unroll
        for (int j = 0; j < 8; ++j) {
            float4 wm = *(const float4*)(mbase + (j << 4) + (p << 2));
            float4 wi = *(const float4*)(ibase + (j << 4) + (p << 2));
            #pragma unroll
            for (int s = 0; s < 4; ++s) {
                float mv = mbr[s][j];
                acc[s][0] += mv * wm.x; acc[s][1] += mv * wm.y;
                acc[s][2] += mv * wm.z; acc[s][3] += mv * wm.w;
            }
            float iv = itv[j];
            pi[0] += iv * wi.x; pi[1] += iv * wi.y;
            pi[2] += iv * wi.z; pi[3] += iv * wi.w;
        }
        float hb = rs4d(pi[0], pi[1], pi[2], pi[3], bb0, bb1) + ab1v[p];
        #pragma unroll
        for (int s = 0; s < 4; ++s) {
            float h = rs4d(acc[s][0], acc[s][1], acc[s][2], acc[s][3], bb0, bb1) + hb;
            logit[s] += fmaxf(h, 0.f) * aw2v[p];
        }
    }
    // quad all-reduce (pure VALU): each quad holds each pass's 4 features once
    #pragma unroll
    for (int s = 0; s < 4; ++s) {
        float v = logit[s];
        v += fdpp<QP_X1>(v);
        v += fdpp<QP_X2>(v);
        logit[s] = v;
    }

    // ---- softmax over 4 members ----
    float l0 = logit[0], l1 = logit[1], l2 = logit[2], l3 = logit[3];
    float mx = fmaxf(fmaxf(l0, l1), fmaxf(l2, l3));
    float e0 = __expf(l0 - mx), e1 = __expf(l1 - mx);
    float e2 = __expf(l2 - mx), e3 = __expf(l3 - mx);
    float den = e0 + e1 + e2 + e3;
    float at0 = e0 / den, at1 = e1 / den, at2 = e2 / den, at3 = e3 / den;

    int best = 0; float bv = at0;
    if (at1 > bv) { bv = at1; best = 1; }
    if (at2 > bv) { bv = at2; best = 2; }
    if (at3 > bv) { bv = at3; best = 3; }
    int pc = (bv * cw1 + cb1) > (bv * cw0 + cb0) ? 1 : 0;

    // group embedding gather (latency hides under phase-B staging)
    float gvr[8];
    {
        const float4* p = (const float4*)group_emb + (((long)g) << 6) + (t << 1);
        float4 v0 = p[0], v1 = p[1];
        gvr[0] = v0.x; gvr[1] = v0.y; gvr[2] = v0.z; gvr[3] = v0.w;
        gvr[4] = v1.x; gvr[5] = v1.y; gvr[6] = v1.z; gvr[7] = v1.w;
    }

    // ---- phase B: stage pred_w1 (overwrites sBuf) ----
    __syncthreads();
    {
        const float4* srcp = (const float4*)pred_w1;     // 1536 float4
        for (int i = tid; i < 1536; i += 256) {
            float4 v = srcp[i];
            int r = i >> 1, cb = (i & 1) << 2;
            *(float4*)(sBuf + 148 * (r >> 4) + 80 * ((r >> 3) & 1) + ((r & 7) << 3) + cb) = v;
        }
    }

    // g_att while staging is in flight
    float gvec[8], elv[8];
    #pragma unroll
    for (int d = 0; d < 8; ++d) {
        float w = at0 * mbr[0][d] + at1 * mbr[1][d] + at2 * mbr[2][d] + at3 * mbr[3][d];
        float ldr = mbr[0][d];
        ldr = (best == 1) ? mbr[1][d] : ldr;
        ldr = (best == 2) ? mbr[2][d] : ldr;
        ldr = (best == 3) ? mbr[3][d] : ldr;
        float ga = pc ? ldr : w;
        float gg = ga + gvr[d];
        gvec[d] = gg;
        elv[d]  = gg * itv[d];
    }
    __syncthreads();

    // ---- prediction MLP: [elem, g, items] (3*256) -> 8 -> 1 ----
    const float* pbase = sBuf + 148 * (t >> 1) + 80 * (t & 1);
    float po[8] = {0.f,0.f,0.f,0.f,0.f,0.f,0.f,0.f};
    #pragma unroll
    for (int j = 0; j < 8; ++j) {
        const float* pA = pbase + (j << 3);
        float4 a0 = *(const float4*)pA,          a1 = *(const float4*)(pA + 4);
        float4 q0 = *(const float4*)(pA + 2368), q1 = *(const float4*)(pA + 2372);
        float4 c0 = *(const float4*)(pA + 4736), c1 = *(const float4*)(pA + 4740);
        float e = elv[j], gg = gvec[j], iv = itv[j];
        po[0] += e * a0.x; po[0] += gg * q0.x; po[0] += iv * c0.x;
        po[1] += e * a0.y; po[1] += gg * q0.y; po[1] += iv * c0.y;
        po[2] += e * a0.z; po[2] += gg * q0.z; po[2] += iv * c0.z;
        po[3] += e * a0.w; po[3] += gg * q0.w; po[3] += iv * c0.w;
        po[4] += e * a1.x; po[4] += gg * q1.x; po[4] += iv * c1.x;
        po[5] += e * a1.y; po[5] += gg * q1.y; po[5] += iv * c1.y;
        po[6] += e * a1.z; po[6] += gg * q1.z; po[6] += iv * c1.z;
        po[7] += e * a1.w; po[7] += gg * q1.w; po[7] += iv * c1.w;
    }
    float poR = rs8d(po[0], po[1], po[2], po[3], po[4], po[5], po[6], po[7],
                     bb0, bb1, bb4);
    float z = fmaxf(poR + pb1v, 0.f) * pw2v;
    z += fdpp<QP_X1>(z);
    z += fdpp<QP_X2>(z);
    z += __shfl_xor(z, 16);
    z += pb2v;
    float y = 1.f / (1.f + __expf(-z));

    // ---- outputs: y[NB] | at_wt[NB*4] | pred_class[NB] ----
    if (t == 0) {
        out[b] = y;
        *(float4*)(out + NB + 4 * b) = make_float4(at0, at1, at2, at3);
        out[5 * NB + b] = (float)pc;
    }
}

extern "C" void kernel_launch(void* const* d_in, const int* in_sizes, int n_in,
                              void* d_out, int out_size, void* d_ws, size_t ws_size,
                              hipStream_t stream) {
    (void)in_sizes; (void)n_in; (void)out_size; (void)d_ws; (void)ws_size;
    agree_kernel<<<NB / GPB, 256, 0, stream>>>(
        (const int*)d_in[0], (const int*)d_in[1], (const int*)d_in[2],
        (const float*)d_in[3], (const float*)d_in[4], (const float*)d_in[5],
        (const float*)d_in[6], (const float*)d_in[7], (const float*)d_in[8],
        (const float*)d_in[9], (const float*)d_in[10], (const float*)d_in[11],
        (const float*)d_in[12], (const float*)d_in[13], (const float*)d_in[14],
        (const float*)d_in[15], (float*)d_out);
}